// Round 1
// 120.317 us; speedup vs baseline: 1.4115x; 1.4115x over previous
//
#include <hip/hip_runtime.h>

typedef unsigned short u16;
typedef unsigned int u32;
typedef __attribute__((ext_vector_type(4))) float f32x4;
typedef __attribute__((ext_vector_type(8))) __bf16 bf16x8;
typedef __attribute__((ext_vector_type(4))) u16 u16x4;
typedef __attribute__((ext_vector_type(4))) float f32x4v;

#define LSEQ 128
#define KW 8
#define NP 2104
#define BATCH 16
#define MTOT 33664   // BATCH*NP
#define FDIM 1088    // PAIR_FEAT
#define GPAD 1152    // 9*128

// ---- workspace layout (bytes) ----
#define WS_W1P  0ul          // u16 [1152*1088] = 2,506,752 B
#define WS_EMOB 2506752ul    // u16 [16*128*512] = 2,097,152 B
#define WS_CAUB 4603904ul    // u16 [16*128*512]
#define WS_SB   6701056ul    // f32 [17*1088] = 73,984 B
#define WS_TABI 6775040ul    // int [2104]
#define WS_TABJ 6783456ul    // int [2104]
#define WS_TABR 6791872ul    // int [2104]
#define WS_EC   6800288ul    // f32 [4096*1152] = 18,874,368 B  (end 25,674,656)

__device__ __forceinline__ u16 f2bf(float x) {
  union { float f; u32 u; } v; v.f = x;
  u32 r = v.u + 0x7fffu + ((v.u >> 16) & 1u);
  return (u16)(r >> 16);
}

__device__ __forceinline__ void load_lds16(const void* g, void* l) {
  __builtin_amdgcn_global_load_lds(
      (const __attribute__((address_space(1))) void*)g,
      (__attribute__((address_space(3))) void*)l, 16, 0, 0);
}

// ---- fused setup ----
// blockIdx.x: [0,1224)     -> W1 -> bf16 padded [1152][1088]
//             [1224,3272)  -> emo/cau -> bf16
//             3272         -> pair tables + out_pos
//             [3273,3346)  -> Sb[r][g] = b1[g] + sum_d smoothed17[r][d]*W1[g][1024+d]  (f32)
__global__ __launch_bounds__(256)
void setup_all(const float* __restrict__ emo, const float* __restrict__ cau,
               const float* __restrict__ pos_emb, const float* __restrict__ W1,
               const float* __restrict__ b1,
               u16* __restrict__ W1p, u16* __restrict__ emoB,
               u16* __restrict__ cauB, float* __restrict__ Sb,
               int* __restrict__ tab_i, int* __restrict__ tab_j,
               int* __restrict__ tab_r, float* __restrict__ out_pos) {
  __shared__ float smL[17 * 64];
  const int bx = blockIdx.x;
  const int t = threadIdx.x;
  if (bx < 1224) {
    int idx = bx * 256 + t;
    if (idx >= 313344) return;
    int g = idx / 272;
    int f = (idx - g * 272) * 4;
    u16x4 o;
    if (g < 1088) {
      f32x4v v = *(const f32x4v*)&W1[g * 1088 + f];
      o.x = f2bf(v.x); o.y = f2bf(v.y); o.z = f2bf(v.z); o.w = f2bf(v.w);
    } else {
      o.x = 0; o.y = 0; o.z = 0; o.w = 0;
    }
    *(u16x4*)&W1p[(size_t)g * 1088 + f] = o;
  } else if (bx < 3272) {
    int idx = (bx - 1224) * 256 + t;
    if (idx < 262144) {
      f32x4v v = *(const f32x4v*)&emo[idx * 4];
      u16x4 o; o.x = f2bf(v.x); o.y = f2bf(v.y); o.z = f2bf(v.z); o.w = f2bf(v.w);
      *(u16x4*)&emoB[idx * 4] = o;
    } else {
      int k = idx - 262144;
      f32x4v v = *(const f32x4v*)&cau[k * 4];
      u16x4 o; o.x = f2bf(v.x); o.y = f2bf(v.y); o.z = f2bf(v.z); o.w = f2bf(v.w);
      *(u16x4*)&cauB[k * 4] = o;
    }
  } else if (bx == 3272) {
    if (t < LSEQ) {
      int i = t;
      int off = 0;
      for (int tt = 0; tt < i; ++tt) {
        int lo = tt - KW; if (lo < 0) lo = 0;
        int hi = tt + KW; if (hi > LSEQ - 1) hi = LSEQ - 1;
        off += hi - lo + 1;
      }
      int jlo = i - KW; if (jlo < 0) jlo = 0;
      int jhi = i + KW; if (jhi > LSEQ - 1) jhi = LSEQ - 1;
      for (int j = jlo; j <= jhi; ++j) {
        int p = off + (j - jlo);
        tab_i[p] = i; tab_j[p] = j; tab_r[p] = j - i;
        out_pos[2 * p]     = (float)(i + 1);
        out_pos[2 * p + 1] = (float)(j + 1);
      }
    }
  } else {
    // Sb blocks: recompute smoothed17 (f32) in LDS, then Sb slice
    for (int idx = t; idx < 17 * 64; idx += 256) {
      int r = idx >> 6, d = idx & 63;
      float acc = 0.f;
      for (int s = 0; s < 17; ++s) {
        float diff = (float)(r - s);
        int a = s - 8; if (a < 0) a = -a;
        float cnt = (float)(128 - a);
        acc += cnt * expf(-diff * diff) * pos_emb[s * 64 + d];
      }
      smL[idx] = acc;
    }
    __syncthreads();
    int idx2 = (bx - 3273) * 256 + t;
    if (idx2 < 17 * 1088) {
      int r = idx2 / 1088;
      int g = idx2 - r * 1088;
      float a = b1[g];
      const float* wr = &W1[(size_t)g * 1088 + 1024];
      const float* sr = &smL[r * 64];
#pragma unroll 8
      for (int d = 0; d < 64; ++d) a = fmaf(sr[d], wr[d], a);
      Sb[r * 1088 + g] = a;
    }
  }
}

// ---- feature GEMM: EC[m][g] = sum_k A[m][k] * W1[g][fsel+k], K=512 ----
// rows 0..2047: emo vs W1[:,0:512); rows 2048..4095: cau vs W1[:,512:1024)
// grid (32 m-tiles, 9 g-tiles), 128x128 tile, 256 thr
__global__ __launch_bounds__(256, 2)
void feat_gemm(const u16* __restrict__ emoB, const u16* __restrict__ cauB,
               const u16* __restrict__ W1p, float* __restrict__ EC) {
  __shared__ __align__(16) u16 As[128 * 32];
  __shared__ __align__(16) u16 Bs[128 * 32];

  const int tid = threadIdx.x;
  const int mblk = blockIdx.x;          // 0..31
  const int gbase = blockIdx.y * 128;   // 0..1024

  const int lane = tid & 63;
  const int w = tid >> 6;
  const int lrow = lane & 15;
  const int lk = (lane >> 4) * 8;
  const int wm = (w >> 1) * 64;
  const int wn = (w & 1) * 64;

  const int row0 = tid >> 2;
  const int sub = (tid & 3) * 8;

  const u16* Asrc = (mblk < 16) ? emoB : cauB;
  const int arow = (mblk & 15) * 128;
  const int fsel = (mblk < 16) ? 0 : 512;

  const u32 a0 = (u32)(arow + row0) * 512 + sub;
  const u32 a1 = a0 + 64 * 512;
  const u32 b0 = (u32)(gbase + row0) * 1088 + fsel + sub;
  const u32 b1o = b0 + 64 * 1088;

  char* AsB = (char*)&As[0] + w * 1024;
  char* BsB = (char*)&Bs[0] + w * 1024;

  f32x4 acc[4][4];
#pragma unroll
  for (int mi = 0; mi < 4; ++mi)
#pragma unroll
    for (int ni = 0; ni < 4; ++ni) acc[mi][ni] = (f32x4){0.f, 0.f, 0.f, 0.f};

  for (int ks = 0; ks < 16; ++ks) {
    const int f0 = ks * 32;
    load_lds16(Asrc + a0 + f0, AsB);
    load_lds16(Asrc + a1 + f0, AsB + 4096);
    load_lds16(W1p + b0 + f0, BsB);
    load_lds16(W1p + b1o + f0, BsB + 4096);
    __syncthreads();

    bf16x8 av[4], bv[4];
#pragma unroll
    for (int mi = 0; mi < 4; ++mi)
      av[mi] = *(const bf16x8*)&As[(wm + mi * 16 + lrow) * 32 + lk];
#pragma unroll
    for (int ni = 0; ni < 4; ++ni)
      bv[ni] = *(const bf16x8*)&Bs[(wn + ni * 16 + lrow) * 32 + lk];
#pragma unroll
    for (int mi = 0; mi < 4; ++mi)
#pragma unroll
      for (int ni = 0; ni < 4; ++ni)
        acc[mi][ni] = __builtin_amdgcn_mfma_f32_16x16x32_bf16(av[mi], bv[ni], acc[mi][ni], 0, 0, 0);
    __syncthreads();
  }

  // store f32 tile; 16-lane groups write full 64B lines
  const int rbase = mblk * 128 + wm + ((lane >> 4) << 2);
#pragma unroll
  for (int mi = 0; mi < 4; ++mi) {
#pragma unroll
    for (int ni = 0; ni < 4; ++ni) {
      const int ocol = gbase + wn + ni * 16 + lrow;
      float* dst = EC + (size_t)(rbase + mi * 16) * GPAD + ocol;
#pragma unroll
      for (int r2 = 0; r2 < 4; ++r2) dst[(size_t)r2 * GPAD] = acc[mi][ni][r2];
    }
  }
}

// ---- combine: pred[q] = b2 + sum_g W2[g]*relu(E[b,i,g]+C[b,j,g]+Sb[r,g]) ----
// wave per pair, lanes over g (f32x4); XCD-chunked block swizzle for L2 locality
__global__ __launch_bounds__(256)
void combine(const float* __restrict__ EC, const float* __restrict__ Sb,
             const float* __restrict__ W2, const float* __restrict__ b2,
             const int* __restrict__ tab_i, const int* __restrict__ tab_j,
             const int* __restrict__ tab_r, float* __restrict__ pred) {
  const int bid = blockIdx.x;                    // 8416 blocks, 8416 = 8*1052
  const int sb = (bid & 7) * 1052 + (bid >> 3);  // bijective XCD chunking
  const int w = threadIdx.x >> 6;
  const int lane = threadIdx.x & 63;
  const int q = sb * 4 + w;      // global pair id [0, 33664)
  const int b = q / NP;
  const int p = q - b * NP;
  const int i = tab_i[p];
  const int j = tab_j[p];
  const int r = tab_r[p];

  const float* e = EC + (size_t)(b * LSEQ + i) * GPAD;
  const float* c = EC + (size_t)(2048 + b * LSEQ + j) * GPAD;
  const float* s = Sb + (r + KW) * FDIM;

  f32x4v acc = {0.f, 0.f, 0.f, 0.f};
#pragma unroll
  for (int it = 0; it < 4; ++it) {
    const int g = it * 256 + (lane << 2);
    f32x4v ev = *(const f32x4v*)(e + g);
    f32x4v cv = *(const f32x4v*)(c + g);
    f32x4v sv = *(const f32x4v*)(s + g);
    f32x4v wv = *(const f32x4v*)(W2 + g);
    float v0 = fmaxf(ev.x + cv.x + sv.x, 0.f);
    float v1 = fmaxf(ev.y + cv.y + sv.y, 0.f);
    float v2 = fmaxf(ev.z + cv.z + sv.z, 0.f);
    float v3 = fmaxf(ev.w + cv.w + sv.w, 0.f);
    acc.x = fmaf(v0, wv.x, acc.x);
    acc.y = fmaf(v1, wv.y, acc.y);
    acc.z = fmaf(v2, wv.z, acc.z);
    acc.w = fmaf(v3, wv.w, acc.w);
  }
  float a = acc.x + acc.y + acc.z + acc.w;
  {
    const int g = 1024 + lane;  // tail: 64 cols, one per lane
    float v = fmaxf(e[g] + c[g] + s[g], 0.f);
    a = fmaf(v, W2[g], a);
  }
  a += __shfl_xor(a, 1);
  a += __shfl_xor(a, 2);
  a += __shfl_xor(a, 4);
  a += __shfl_xor(a, 8);
  a += __shfl_xor(a, 16);
  a += __shfl_xor(a, 32);
  if (lane == 0) pred[q] = a + b2[0];
}

extern "C" void kernel_launch(void* const* d_in, const int* in_sizes, int n_in,
                              void* d_out, int out_size, void* d_ws, size_t ws_size,
                              hipStream_t stream) {
  const float* h_emo = (const float*)d_in[0];
  const float* h_cau = (const float*)d_in[1];
  const float* pos_emb = (const float*)d_in[2];
  const float* W1 = (const float*)d_in[3];
  const float* b1 = (const float*)d_in[4];
  const float* W2 = (const float*)d_in[5];
  const float* b2 = (const float*)d_in[6];

  char* ws = (char*)d_ws;
  u16* W1p = (u16*)(ws + WS_W1P);
  u16* emoB = (u16*)(ws + WS_EMOB);
  u16* cauB = (u16*)(ws + WS_CAUB);
  float* Sb = (float*)(ws + WS_SB);
  int* tab_i = (int*)(ws + WS_TABI);
  int* tab_j = (int*)(ws + WS_TABJ);
  int* tab_r = (int*)(ws + WS_TABR);
  float* EC = (float*)(ws + WS_EC);

  float* pred = (float*)d_out;
  float* out_pos = (float*)d_out + MTOT;

  setup_all<<<3346, 256, 0, stream>>>(h_emo, h_cau, pos_emb, W1, b1,
                                      W1p, emoB, cauB, Sb,
                                      tab_i, tab_j, tab_r, out_pos);
  feat_gemm<<<dim3(32, 9), 256, 0, stream>>>(emoB, cauB, W1p, EC);
  combine<<<8416, 256, 0, stream>>>(EC, Sb, W2, b2, tab_i, tab_j, tab_r, pred);
}

// Round 2
// 109.943 us; speedup vs baseline: 1.5447x; 1.0944x over previous
//
#include <hip/hip_runtime.h>

typedef unsigned short u16;
typedef unsigned int u32;
typedef __attribute__((ext_vector_type(4))) float f32x4;
typedef __attribute__((ext_vector_type(8))) __bf16 bf16x8;
typedef __attribute__((ext_vector_type(4))) u16 u16x4;
typedef __attribute__((ext_vector_type(4))) float f32x4v;

#define LSEQ 128
#define KW 8
#define NP 2104
#define BATCH 16
#define MTOT 33664   // BATCH*NP
#define FDIM 1088    // PAIR_FEAT
#define GPAD 1152    // 9*128

// ---- workspace layout (bytes) ----
#define WS_W1P  0ul          // u16 [1152*1088] = 2,506,752 B
#define WS_EMOB 2506752ul    // u16 [16*128*512] = 2,097,152 B
#define WS_CAUB 4603904ul    // u16 [16*128*512]
#define WS_SB   6701056ul    // u16 [17*1088] = 36,992 B (bf16)
#define WS_TOFF 6738048ul    // int [128]
#define WS_EC   6738560ul    // f32 [4096*1152] = 18,874,368 B (end 25,612,928)

__device__ __forceinline__ u16 f2bf(float x) {
  union { float f; u32 u; } v; v.f = x;
  u32 r = v.u + 0x7fffu + ((v.u >> 16) & 1u);
  return (u16)(r >> 16);
}

__device__ __forceinline__ float bf2f(u16 x) {
  union { u32 u; float f; } v; v.u = ((u32)x) << 16; return v.f;
}

__device__ __forceinline__ void load_lds16(const void* g, void* l) {
  __builtin_amdgcn_global_load_lds(
      (const __attribute__((address_space(1))) void*)g,
      (__attribute__((address_space(3))) void*)l, 16, 0, 0);
}

// ---- fused setup ----
// blockIdx.x: [0,1224)     -> W1 -> bf16 padded [1152][1088]
//             [1224,3272)  -> emo/cau -> bf16
//             3272         -> tab_off + out_pos
//             [3273,3346)  -> Sb[r][g] = bf16(b1[g] + sum_d sm17[r][d]*W1[g][1024+d])
__global__ __launch_bounds__(256)
void setup_all(const float* __restrict__ emo, const float* __restrict__ cau,
               const float* __restrict__ pos_emb, const float* __restrict__ W1,
               const float* __restrict__ b1,
               u16* __restrict__ W1p, u16* __restrict__ emoB,
               u16* __restrict__ cauB, u16* __restrict__ Sb,
               int* __restrict__ tab_off, float* __restrict__ out_pos) {
  __shared__ float smL[17 * 64];
  const int bx = blockIdx.x;
  const int t = threadIdx.x;
  if (bx < 1224) {
    int idx = bx * 256 + t;
    if (idx >= 313344) return;
    int g = idx / 272;
    int f = (idx - g * 272) * 4;
    u16x4 o;
    if (g < 1088) {
      f32x4v v = *(const f32x4v*)&W1[g * 1088 + f];
      o.x = f2bf(v.x); o.y = f2bf(v.y); o.z = f2bf(v.z); o.w = f2bf(v.w);
    } else {
      o.x = 0; o.y = 0; o.z = 0; o.w = 0;
    }
    *(u16x4*)&W1p[(size_t)g * 1088 + f] = o;
  } else if (bx < 3272) {
    int idx = (bx - 1224) * 256 + t;
    if (idx < 262144) {
      f32x4v v = *(const f32x4v*)&emo[idx * 4];
      u16x4 o; o.x = f2bf(v.x); o.y = f2bf(v.y); o.z = f2bf(v.z); o.w = f2bf(v.w);
      *(u16x4*)&emoB[idx * 4] = o;
    } else {
      int k = idx - 262144;
      f32x4v v = *(const f32x4v*)&cau[k * 4];
      u16x4 o; o.x = f2bf(v.x); o.y = f2bf(v.y); o.z = f2bf(v.z); o.w = f2bf(v.w);
      *(u16x4*)&cauB[k * 4] = o;
    }
  } else if (bx == 3272) {
    if (t < LSEQ) {
      int i = t;
      int off = 0;
      for (int tt = 0; tt < i; ++tt) {
        int lo = tt - KW; if (lo < 0) lo = 0;
        int hi = tt + KW; if (hi > LSEQ - 1) hi = LSEQ - 1;
        off += hi - lo + 1;
      }
      tab_off[i] = off;
      int jlo = i - KW; if (jlo < 0) jlo = 0;
      int jhi = i + KW; if (jhi > LSEQ - 1) jhi = LSEQ - 1;
      for (int j = jlo; j <= jhi; ++j) {
        int p = off + (j - jlo);
        out_pos[2 * p]     = (float)(i + 1);
        out_pos[2 * p + 1] = (float)(j + 1);
      }
    }
  } else {
    // Sb blocks: recompute smoothed17 (f32) in LDS, then Sb slice -> bf16
    for (int idx = t; idx < 17 * 64; idx += 256) {
      int r = idx >> 6, d = idx & 63;
      float acc = 0.f;
      for (int s = 0; s < 17; ++s) {
        float diff = (float)(r - s);
        int a = s - 8; if (a < 0) a = -a;
        float cnt = (float)(128 - a);
        acc += cnt * expf(-diff * diff) * pos_emb[s * 64 + d];
      }
      smL[idx] = acc;
    }
    __syncthreads();
    int idx2 = (bx - 3273) * 256 + t;
    if (idx2 < 17 * 1088) {
      int r = idx2 / 1088;
      int g = idx2 - r * 1088;
      float a = b1[g];
      const float* wr = &W1[(size_t)g * 1088 + 1024];
      const float* sr = &smL[r * 64];
#pragma unroll 8
      for (int d = 0; d < 64; ++d) a = fmaf(sr[d], wr[d], a);
      Sb[r * 1088 + g] = f2bf(a);
    }
  }
}

// ---- feature GEMM: EC[m][g] = sum_k A[m][k] * W1[g][fsel+k], K=512 ----
// rows 0..2047: emo; rows 2048..4095: cau. BM=64, BN=128 -> grid (64, 9)
__global__ __launch_bounds__(256, 4)
void feat_gemm(const u16* __restrict__ emoB, const u16* __restrict__ cauB,
               const u16* __restrict__ W1p, float* __restrict__ EC) {
  __shared__ __align__(16) u16 As[64 * 32];
  __shared__ __align__(16) u16 Bs[128 * 32];

  const int tid = threadIdx.x;
  const int mblk = blockIdx.x;          // 0..63
  const int gbase = blockIdx.y * 128;   // 0..1024

  const int lane = tid & 63;
  const int w = tid >> 6;
  const int lrow = lane & 15;
  const int lk = (lane >> 4) * 8;
  const int wm = (w >> 1) * 32;
  const int wn = (w & 1) * 64;

  const int row0 = tid >> 2;            // 0..63
  const int sub = (tid & 3) * 8;

  const u16* Asrc = (mblk < 32) ? emoB : cauB;
  const int arow = (mblk & 31) * 64;
  const int fsel = (mblk < 32) ? 0 : 512;

  const u32 a0 = (u32)(arow + row0) * 512 + sub;
  const u32 b0 = (u32)(gbase + row0) * 1088 + fsel + sub;
  const u32 b1o = b0 + 64u * 1088;

  char* AsD = (char*)&As[0] + tid * 16;
  char* BsD = (char*)&Bs[0] + tid * 16;

  f32x4 acc[2][4];
#pragma unroll
  for (int mi = 0; mi < 2; ++mi)
#pragma unroll
    for (int ni = 0; ni < 4; ++ni) acc[mi][ni] = (f32x4){0.f, 0.f, 0.f, 0.f};

  for (int ks = 0; ks < 16; ++ks) {
    const int f0 = ks * 32;
    load_lds16(Asrc + a0 + f0, AsD);
    load_lds16(W1p + b0 + f0, BsD);
    load_lds16(W1p + b1o + f0, BsD + 4096);
    __syncthreads();

    bf16x8 av[2], bv[4];
#pragma unroll
    for (int mi = 0; mi < 2; ++mi)
      av[mi] = *(const bf16x8*)&As[(wm + mi * 16 + lrow) * 32 + lk];
#pragma unroll
    for (int ni = 0; ni < 4; ++ni)
      bv[ni] = *(const bf16x8*)&Bs[(wn + ni * 16 + lrow) * 32 + lk];
#pragma unroll
    for (int mi = 0; mi < 2; ++mi)
#pragma unroll
      for (int ni = 0; ni < 4; ++ni)
        acc[mi][ni] = __builtin_amdgcn_mfma_f32_16x16x32_bf16(av[mi], bv[ni], acc[mi][ni], 0, 0, 0);
    __syncthreads();
  }

  const int rbase = mblk * 64 + wm + ((lane >> 4) << 2);
#pragma unroll
  for (int mi = 0; mi < 2; ++mi) {
#pragma unroll
    for (int ni = 0; ni < 4; ++ni) {
      const int ocol = gbase + wn + ni * 16 + lrow;
      float* dst = EC + (size_t)(rbase + mi * 16) * GPAD + ocol;
#pragma unroll
      for (int r2 = 0; r2 < 4; ++r2) dst[(size_t)r2 * GPAD] = acc[mi][ni][r2];
    }
  }
}

// ---- combine: wave per (b,i)-row g-half; E,W2 in regs; S in LDS; C prefetched ----
// pred[q] = b2 + sum_g W2[g]*relu(E[b,i,g]+C[b,j,g]+S[r,g])
__global__ __launch_bounds__(256, 4)
void combine(const float* __restrict__ EC, const u16* __restrict__ Sb,
             const float* __restrict__ W2, const float* __restrict__ b2,
             const int* __restrict__ tab_off, float* __restrict__ pred) {
  __shared__ __align__(16) u16 Sl[17 * 1088];   // 36,992 B
  __shared__ float partA[2][17], partB[2][17];

  const int tid = threadIdx.x;
  const int bid = blockIdx.x;                   // 1024 = 8*128
  const int sb = (bid & 7) * 128 + (bid >> 3);  // XCD-chunked, bijective

  // stage S -> LDS (linear dest = base + tid*16)
  {
    char* dst = (char*)&Sl[0];
    const char* src = (const char*)Sb;
#pragma unroll
    for (int it = 0; it < 9; ++it)
      load_lds16(src + it * 4096 + tid * 16, dst + it * 4096 + tid * 16);
    if (tid < 8)
      load_lds16(src + 36864 + tid * 16, dst + 36864 + tid * 16);
  }

  const int w = tid >> 6;
  const int lane = tid & 63;
  const int h = w >> 1;       // which (b,i) of this block
  const int gh = w & 1;       // which g-half
  const int u = sb * 2 + h;
  const int b = u >> 7;
  const int i = u & 127;
  int jlo = i - KW; if (jlo < 0) jlo = 0;
  int jhi = i + KW; if (jhi > 127) jhi = 127;

  const float bias2 = b2[0];
  const float* Erow = EC + (size_t)(b * 128 + i) * GPAD;
  const float* Cbase = EC + (size_t)(2048 + b * 128) * GPAD;

  // per-lane g slice: gh0 -> [0,512), gh1 -> [512,1024) + tail 1024+lane
  const int g0 = gh * 512 + lane * 4;
  const int g1 = g0 + 256;
  const f32x4v e0 = *(const f32x4v*)(Erow + g0);
  const f32x4v e1 = *(const f32x4v*)(Erow + g1);
  const f32x4v w20 = *(const f32x4v*)(W2 + g0);
  const f32x4v w21 = *(const f32x4v*)(W2 + g1);
  float eT = 0.f, w2T = 0.f;
  if (gh) { eT = Erow[1024 + lane]; w2T = W2[1024 + lane]; }

  __syncthreads();  // S staged (barrier drains vmcnt)

  const float* Crow = Cbase + (size_t)jlo * GPAD;
  f32x4v c0 = *(const f32x4v*)(Crow + g0);
  f32x4v c1 = *(const f32x4v*)(Crow + g1);
  float cT = gh ? Crow[1024 + lane] : 0.f;

  for (int j = jlo; j <= jhi; ++j) {
    f32x4v n0 = c0, n1 = c1; float nT = cT;
    if (j < jhi) {
      const float* Nrow = Cbase + (size_t)(j + 1) * GPAD;
      n0 = *(const f32x4v*)(Nrow + g0);
      n1 = *(const f32x4v*)(Nrow + g1);
      if (gh) nT = Nrow[1024 + lane];
    }
    const int r = j - i + KW;
    const u16* srow = &Sl[r * 1088];
    u16x4 sa = *(const u16x4*)(srow + g0);
    u16x4 sc = *(const u16x4*)(srow + g1);

    float a = 0.f;
    a = fmaf(fmaxf(e0.x + c0.x + bf2f(sa.x), 0.f), w20.x, a);
    a = fmaf(fmaxf(e0.y + c0.y + bf2f(sa.y), 0.f), w20.y, a);
    a = fmaf(fmaxf(e0.z + c0.z + bf2f(sa.z), 0.f), w20.z, a);
    a = fmaf(fmaxf(e0.w + c0.w + bf2f(sa.w), 0.f), w20.w, a);
    a = fmaf(fmaxf(e1.x + c1.x + bf2f(sc.x), 0.f), w21.x, a);
    a = fmaf(fmaxf(e1.y + c1.y + bf2f(sc.y), 0.f), w21.y, a);
    a = fmaf(fmaxf(e1.z + c1.z + bf2f(sc.z), 0.f), w21.z, a);
    a = fmaf(fmaxf(e1.w + c1.w + bf2f(sc.w), 0.f), w21.w, a);
    if (gh) {
      float sT = bf2f(srow[1024 + lane]);
      a = fmaf(fmaxf(eT + cT + sT, 0.f), w2T, a);
    }

    a += __shfl_xor(a, 1);
    a += __shfl_xor(a, 2);
    a += __shfl_xor(a, 4);
    a += __shfl_xor(a, 8);
    a += __shfl_xor(a, 16);
    a += __shfl_xor(a, 32);
    if (lane == 0) {
      if (gh) partB[h][j - jlo] = a;
      else    partA[h][j - jlo] = a;
    }
    c0 = n0; c1 = n1; cT = nT;
  }
  __syncthreads();

  // finalize: wave 0 -> h=0, wave 1 -> h=1
  if (w < 2) {
    const int u2 = sb * 2 + w;
    const int bb = u2 >> 7;
    const int i2 = u2 & 127;
    int jl2 = i2 - KW; if (jl2 < 0) jl2 = 0;
    int jh2 = i2 + KW; if (jh2 > 127) jh2 = 127;
    const int cnt2 = jh2 - jl2 + 1;
    if (lane < cnt2) {
      const int q = bb * NP + tab_off[i2] + lane;
      pred[q] = partA[w][lane] + partB[w][lane] + bias2;
    }
  }
}

extern "C" void kernel_launch(void* const* d_in, const int* in_sizes, int n_in,
                              void* d_out, int out_size, void* d_ws, size_t ws_size,
                              hipStream_t stream) {
  const float* h_emo = (const float*)d_in[0];
  const float* h_cau = (const float*)d_in[1];
  const float* pos_emb = (const float*)d_in[2];
  const float* W1 = (const float*)d_in[3];
  const float* b1 = (const float*)d_in[4];
  const float* W2 = (const float*)d_in[5];
  const float* b2 = (const float*)d_in[6];

  char* ws = (char*)d_ws;
  u16* W1p = (u16*)(ws + WS_W1P);
  u16* emoB = (u16*)(ws + WS_EMOB);
  u16* cauB = (u16*)(ws + WS_CAUB);
  u16* Sb = (u16*)(ws + WS_SB);
  int* tab_off = (int*)(ws + WS_TOFF);
  float* EC = (float*)(ws + WS_EC);

  float* pred = (float*)d_out;
  float* out_pos = (float*)d_out + MTOT;

  setup_all<<<3346, 256, 0, stream>>>(h_emo, h_cau, pos_emb, W1, b1,
                                      W1p, emoB, cauB, Sb, tab_off, out_pos);
  feat_gemm<<<dim3(64, 9), 256, 0, stream>>>(emoB, cauB, W1p, EC);
  combine<<<1024, 256, 0, stream>>>(EC, Sb, W2, b2, tab_off, pred);
}